// Round 11
// baseline (7207.239 us; speedup 1.0000x reference)
//
#include <hip/hip_runtime.h>
#include <math.h>

typedef __bf16 bf16;
typedef __attribute__((ext_vector_type(8))) __bf16 bf16x8;
typedef __attribute__((ext_vector_type(4))) float f32x4;
typedef __attribute__((ext_vector_type(4))) int i32x4;

// CK-style direct intrinsic binding: buffer load with explicit cache policy.
// cpol=1 -> sc0: bypass L1, served/allocated at L2.
extern "C" __device__ i32x4 llvm_amdgcn_raw_buffer_load_v4i32(
    i32x4 rsrc, int voffset, int soffset, int cpol) __asm("llvm.amdgcn.raw.buffer.load.v4i32");

static constexpr int B = 256, L = 512, D = 64, P = 256, H = 512, M = 256, HOR = 9;
static constexpr int G = 2048;
static constexpr int K0 = P + H;      // 768
static constexpr int K1 = 2 * H;      // 1024
static constexpr float EPS = 1e-5f;
static constexpr int NB = 4;          // rolling A-prefetch depth (chunks)
static constexpr int LDS_BYTES = 163840;   // W-hi(max 128K) + 2x16K A dbuf

#define MFMA(a, b, c) __builtin_amdgcn_mfma_f32_16x16x32_bf16((a), (b), (c), 0, 0, 0)

__device__ __forceinline__ float sigmoidf_(float x) { return 1.0f / (1.0f + expf(-x)); }
__device__ __forceinline__ float gelu_exact(float x) {
    return 0.5f * x * (1.0f + erff(x * 0.70710678118654752f));
}

// Chunk barrier: publish LDS writes (lgkmcnt only) WITHOUT draining vmcnt.
// sched_barrier pair required (rule #18).
__device__ __forceinline__ void lds_barrier() {
    asm volatile("s_waitcnt lgkmcnt(0)" ::: "memory");
    __builtin_amdgcn_sched_barrier(0);
    __builtin_amdgcn_s_barrier();
    __builtin_amdgcn_sched_barrier(0);
}

// Device-coherent 16B load (2 x 8B agent-scope relaxed atomic loads -> sc1,
// reads past any stale per-XCD L2). For CROSS-XCD state only.
__device__ __forceinline__ bf16x8 cload(const bf16* p) {
    union { unsigned long long u[2]; bf16x8 v; } r;
    const unsigned long long* q = (const unsigned long long*)p;
    r.u[0] = __hip_atomic_load(q,     __ATOMIC_RELAXED, __HIP_MEMORY_SCOPE_AGENT);
    r.u[1] = __hip_atomic_load(q + 1, __ATOMIC_RELAXED, __HIP_MEMORY_SCOPE_AGENT);
    return r.v;
}

// sc0 buffer load: L1-bypass, L2-served. Co-XCD state only (producer's sc1
// write-through leaves local L2 updated-or-absent, never stale — R7-R10
// HW-validated: correct results + FETCH collapse to ~1 MB/tick).
__device__ __forceinline__ i32x4 make_rsrc(const void* p, unsigned bytes) {
    union { const void* p; unsigned u[2]; } a; a.p = p;
    i32x4 r;
    r.x = (int)a.u[0];
    r.y = (int)(a.u[1] & 0xFFFFu);     // base[47:32], stride=0
    r.z = (int)bytes;                  // num_records (bytes, stride==0)
    r.w = 0x00020000;                  // raw untyped dword access
    return r;
}
__device__ __forceinline__ bf16x8 bload_sc0(i32x4 rsrc, int voff) {
    union { i32x4 i; bf16x8 b; } u;
    u.i = llvm_amdgcn_raw_buffer_load_v4i32(rsrc, voff, 0, 1 /*sc0*/);
    return u.b;
}

// ---------------------------------------------------------------------------
// emb = gelu(LN(x@Wp+bp)) -> bf16 hi/lo, T-MAJOR: [(t*B + b)*P + p]
// ---------------------------------------------------------------------------
__global__ __launch_bounds__(256) void emb_kernel(
    const float* __restrict__ x, const float* __restrict__ Wp,
    const float* __restrict__ bp, const float* __restrict__ gamma,
    const float* __restrict__ beta, bf16* __restrict__ ehi,
    bf16* __restrict__ elo, int use_elo)
{
    const int row = blockIdx.x;          // b*L + t
    const int b   = row >> 9;
    const int t   = row & (L - 1);
    const int p   = threadIdx.x;
    __shared__ float xs[D];
    __shared__ float red[P];

    if (p < D) xs[p] = x[(size_t)row * D + p];
    __syncthreads();

    float acc = bp[p];
#pragma unroll
    for (int k = 0; k < D; ++k) acc = fmaf(xs[k], Wp[k * P + p], acc);

    red[p] = acc;
    __syncthreads();
    for (int s = 128; s > 0; s >>= 1) { if (p < s) red[p] += red[p + s]; __syncthreads(); }
    const float mu = red[0] * (1.0f / (float)P);
    __syncthreads();
    const float d = acc - mu;
    red[p] = d * d;
    __syncthreads();
    for (int s = 128; s > 0; s >>= 1) { if (p < s) red[p] += red[p + s]; __syncthreads(); }
    const float var = red[0] * (1.0f / (float)P);

    const float v = gelu_exact(gamma[p] * d * rsqrtf(var + EPS) + beta[p]);
    const size_t o = ((size_t)t * B + b) * P + p;
    const bf16 hh = (bf16)v;
    ehi[o] = hh;
    if (use_elo) elo[o] = (bf16)(v - (float)hh);
}

// ---------------------------------------------------------------------------
// weight prep in FRAG-LINEAR order: for (ng, S, wc, lane):
//   8 bf16 at W[g = wc*512 + ng*16 + (lane&15)][k = S*32 + (lane>>4)*8 ..+8]
// linear index = (((ng*(K/32) + S)*4 + wc)*64 + lane)*8
// ---------------------------------------------------------------------------
__global__ __launch_bounds__(64) void prep_w_frag(
    const float* __restrict__ Wih, const float* __restrict__ Whh, int Kih,
    bf16* __restrict__ hi, bf16* __restrict__ lo)
{
    const int ng = blockIdx.x, S = blockIdx.y, wc = blockIdx.z;
    const int lane = threadIdx.x;
    const int g = wc * 512 + ng * 16 + (lane & 15);
    const int kbase = S * 32 + (lane >> 4) * 8;
    const size_t out = ((((size_t)ng * gridDim.y + S) * 4 + wc) * 64 + lane) * 8;
#pragma unroll
    for (int e = 0; e < 8; ++e) {
        const int k = kbase + e;
        const float v = (k < Kih) ? Wih[(size_t)g * Kih + k]
                                  : Whh[(size_t)g * 512 + (k - Kih)];
        const bf16 h = (bf16)v;
        hi[out + e] = h;
        lo[out + e] = (bf16)(v - (float)h);
    }
}

__global__ __launch_bounds__(256) void prep_bias(
    const float* __restrict__ bih0, const float* __restrict__ bhh0,
    const float* __restrict__ bih1, const float* __restrict__ bhh1,
    float* __restrict__ bsum0, float* __restrict__ bsum1)
{
    const int g = blockIdx.x * 256 + threadIdx.x;   // grid.x = 8
    bsum0[g] = bih0[g] + bhh0[g];
    bsum1[g] = bih1[g] + bhh1[g];
}

// ---------------------------------------------------------------------------
// Persistent recurrence, 256 blocks x 512 THREADS (8 waves, 1 block/CU).
//
// R11 re-tiling: LDS b128 READS are the critical resource (model: 1280
// reads x 12 cy = 6.4 us of the 9.9 us tick). Read amplification is set by
// wave tiling: R9's (2 row-tiles x 1 col, full K) makes every A fragment
// read by 4 waves, Whi by 2 (1.25 MB/tick/CU). New tiling: wave (rp,cp,kh)
// owns 2 row-tiles x 2 COL-tiles over the kh-PARITY chunks (half of K).
// A amp 4->2, Whi amp 2->2, total 768 KB (-40%). Staging, swizzle, frag
// layouts, C/D parking mapping all UNCHANGED. W-lo regs/wave unchanged
// (2 cols x K/2 = 24/32 frags, static index). K-halves merge in Gs via
// two-phase park (kh=0 writes, barrier, kh=1 adds) — no atomics.
//
// Coherence (R7-R10 scheme, HW-validated): no invalidates. State writes sc1
// write-through; co-XCD state reads sc0 (L2-served); cross-XCD reads (L1's
// h0) sc1; immutable data plain. R4 decode: XCD = bid%8 = layer*4+mg is
// producer-pure; 64-block group barrier per tick.
// ---------------------------------------------------------------------------
struct RArgs {
    int use_elo;
    const bf16 *ehi, *elo;
    const bf16 *W0hif, *W0lof, *W1hif, *W1lof;   // frag-linear
    const float *bsum0, *bsum1;
    bf16 *h0hi[2], *h0lo[2], *h1hi[2], *h1lo[2];
    unsigned int* bar;    // 4 counters, 256B apart
};

template <int NC, int LAYER>
__device__ __forceinline__ void tick_body(
    int tid, int lane, int rp, int cp, int kh,
    int grow, int kin, int slot,
    const bf16* __restrict__ a0h, const bf16* __restrict__ a0l,
    i32x4 r1h, i32x4 r1l,
    char* lds, const bf16x8* wlo_own,
    float bI0, float bI1, float bF0, float bF1,
    float bG0, float bG1, float bO0, float bO1,
    float& c0r, float& c1r,
    unsigned int* hw_hi, unsigned int* hw_lo,
    int m, int jp)
{
    constexpr int K0seg = (LAYER == 0) ? 256 : 512;
    constexpr int AS0   = (LAYER == 0) ? 256 : 512;

    const bf16* wlds = (const bf16*)lds;
    char* dbuf = lds + 131072;
    float (*Gs)[68] = (float(*)[68])(lds + 131072);

    auto cloadA = [&](int c, int hf) -> bf16x8 {
        const int kk = c * 64 + kin;
        if (kk < K0seg) {
            const bf16* p = (hf ? a0l : a0h) + (size_t)grow * AS0 + kk;
            if (LAYER == 0) return *(const bf16x8*)p;   // emb: immutable, plain
            return cload(p);                            // h0 cross-XCD: sc1
        }
        // co-XCD state (L0: h0; L1: h1) -> sc0 (L2-served, shared on XCD)
        return bload_sc0(hf ? r1l : r1h, ((grow << 9) + (kk - K0seg)) * 2);
    };
    auto stageW = [&](const bf16x8& v, int pb, int hf) {
        *(bf16x8*)(dbuf + pb * 16384 + hf * 8192 + slot * 16) = v;
    };

    // accumulators: [row-tile-pair][col-pair] x 3 products
    f32x4 hh[2][2], lh[2][2], hl[2][2];
#pragma unroll
    for (int i = 0; i < 2; ++i)
#pragma unroll
        for (int k2 = 0; k2 < 2; ++k2) {
            hh[i][k2] = f32x4{0.f,0.f,0.f,0.f};
            lh[i][k2] = f32x4{0.f,0.f,0.f,0.f};
            hl[i][k2] = f32x4{0.f,0.f,0.f,0.f};
        }

    // rolling A prefetch (NB chunks deep, both halves per thread)
    bf16x8 aregH[NB], aregL[NB];
#pragma unroll
    for (int i = 0; i < NB; ++i) { aregH[i] = cloadA(i, 0); aregL[i] = cloadA(i, 1); }
    stageW(aregH[0], 0, 0);
    stageW(aregL[0], 0, 1);
    aregH[0] = cloadA(NB, 0);
    aregL[0] = cloadA(NB, 1);
    lds_barrier();

#pragma unroll
    for (int c = 0; c < NC; ++c) {
        if (c + 1 < NC) {
            stageW(aregH[(c + 1) % NB], (c + 1) & 1, 0);
            stageW(aregL[(c + 1) % NB], (c + 1) & 1, 1);
            if (c + 1 + NB < NC) {
                aregH[(c + 1) % NB] = cloadA(c + 1 + NB, 0);
                aregL[(c + 1) % NB] = cloadA(c + 1 + NB, 1);
            }
        }
        if ((c & 1) == kh) {                 // this wave's K-parity
            const int cl = c >> 1;           // local chunk index (compile-time)
            const char* bufc = dbuf + (c & 1) * 16384;
#pragma unroll
            for (int s2 = 0; s2 < 2; ++s2) {
                const int S = c * 2 + s2;
                const int swz = ((s2 * 4) + (lane >> 4)) << 4;
                bf16x8 Whi0 = *(const bf16x8*)((const char*)wlds + ((S * 4 + cp * 2    ) * 64 + lane) * 16);
                bf16x8 Whi1 = *(const bf16x8*)((const char*)wlds + ((S * 4 + cp * 2 + 1) * 64 + lane) * 16);
                const bf16x8 Wlo0 = wlo_own[(cl * 2 + s2) * 2 + 0];   // static
                const bf16x8 Wlo1 = wlo_own[(cl * 2 + s2) * 2 + 1];   // static
#pragma unroll
                for (int rt = 0; rt < 2; ++rt) {
                    const int row_tile = rp + rt * 2;
                    const int ofsA = (((s2 * 4 + row_tile) * 64 + lane) * 16) ^ swz;
                    bf16x8 Ahi = *(const bf16x8*)(bufc + ofsA);
                    bf16x8 Alo = *(const bf16x8*)(bufc + 8192 + ofsA);
                    hh[rt][0] = MFMA(Ahi, Whi0, hh[rt][0]);
                    hh[rt][1] = MFMA(Ahi, Whi1, hh[rt][1]);
                    lh[rt][0] = MFMA(Alo, Whi0, lh[rt][0]);
                    lh[rt][1] = MFMA(Alo, Whi1, lh[rt][1]);
                    hl[rt][0] = MFMA(Ahi, Wlo0, hl[rt][0]);
                    hl[rt][1] = MFMA(Ahi, Wlo1, hl[rt][1]);
                }
            }
        }
        lds_barrier();   // publish next stage; vmem prefetch stays in flight
    }

    // two-phase park: kh=0 writes its K-half, then kh=1 adds its K-half.
    if (kh == 0) {
#pragma unroll
        for (int rt = 0; rt < 2; ++rt)
#pragma unroll
            for (int cc = 0; cc < 2; ++cc)
#pragma unroll
                for (int r = 0; r < 4; ++r) {
                    const int row = (rp + rt * 2) * 16 + (lane >> 4) * 4 + r;
                    const int col = (cp * 2 + cc) * 16 + (lane & 15);
                    Gs[row][col] = hh[rt][cc][r] + lh[rt][cc][r] + hl[rt][cc][r];
                }
    }
    lds_barrier();
    if (kh == 1) {
#pragma unroll
        for (int rt = 0; rt < 2; ++rt)
#pragma unroll
            for (int cc = 0; cc < 2; ++cc)
#pragma unroll
                for (int r = 0; r < 4; ++r) {
                    const int row = (rp + rt * 2) * 16 + (lane >> 4) * 4 + r;
                    const int col = (cp * 2 + cc) * 16 + (lane & 15);
                    Gs[row][col] += hh[rt][cc][r] + lh[rt][cc][r] + hl[rt][cc][r];
                }
    }
    lds_barrier();

    // pointwise: all 512 threads, (m, jp..jp+1)
    {
        float hv0, hv1;
        {
            const float iraw = Gs[m][jp]      + bI0;
            const float fraw = Gs[m][16 + jp] + bF0;
            const float graw = Gs[m][32 + jp] + bG0;
            const float oraw = Gs[m][48 + jp] + bO0;
            const float cv = sigmoidf_(fraw) * c0r + sigmoidf_(iraw) * tanhf(graw);
            c0r = cv;
            hv0 = sigmoidf_(oraw) * tanhf(cv);
        }
        {
            const float iraw = Gs[m][jp + 1]      + bI1;
            const float fraw = Gs[m][16 + jp + 1] + bF1;
            const float graw = Gs[m][32 + jp + 1] + bG1;
            const float oraw = Gs[m][48 + jp + 1] + bO1;
            const float cv = sigmoidf_(fraw) * c1r + sigmoidf_(iraw) * tanhf(graw);
            c1r = cv;
            hv1 = sigmoidf_(oraw) * tanhf(cv);
        }
        union { unsigned int u; bf16 b[2]; } ph, pl;
        ph.b[0] = (bf16)hv0; ph.b[1] = (bf16)hv1;
        pl.b[0] = (bf16)(hv0 - (float)ph.b[0]);
        pl.b[1] = (bf16)(hv1 - (float)ph.b[1]);
        // agent-scope write-through: LLC-visible once vmcnt drains; local L2
        // left updated-or-absent (never stale) for next tick's sc0 readers.
        __hip_atomic_store(hw_hi, ph.u, __ATOMIC_RELAXED, __HIP_MEMORY_SCOPE_AGENT);
        __hip_atomic_store(hw_lo, pl.u, __ATOMIC_RELAXED, __HIP_MEMORY_SCOPE_AGENT);
    }
}

// group barrier: 64 blocks of row-group mg (XCD mg + XCD 4+mg). No cache
// maintenance — scope-precise loads make it unnecessary (R7-R10-validated).
__device__ __forceinline__ void group_bar(unsigned int* bar, int t) {
    __syncthreads();   // drains vmcnt -> agent stores visible at LLC
    if (threadIdx.x == 0) {
        __hip_atomic_fetch_add(bar, 1u, __ATOMIC_RELAXED, __HIP_MEMORY_SCOPE_AGENT);
        const unsigned int target = 64u * (unsigned)(t + 1);
        while (__hip_atomic_load(bar, __ATOMIC_RELAXED, __HIP_MEMORY_SCOPE_AGENT) < target)
            __builtin_amdgcn_s_sleep(1);
        __builtin_amdgcn_fence(__ATOMIC_ACQUIRE, "workgroup");
    }
    __syncthreads();
}

__global__ __launch_bounds__(512, 1) void recurrence_kernel(RArgs a)
{
    extern __shared__ __align__(16) char lds[];

    // R4 decode: XCD = bid%8 = layer*4+mg (producer-pure per XCD); all 32
    // ng-blocks of one (layer,mg) are co-XCD and time-aligned.
    const int bid   = blockIdx.x;
    const int layer = (bid >> 2) & 1;
    const int mg    = bid & 3;
    const int ng    = bid >> 3;
    const int bm0 = mg * 64, j0 = ng * 16;

    const int tid  = threadIdx.x;            // 0..511
    const int lane = tid & 63;
    const int wid  = tid >> 6;                // 0..7
    const int kh = wid & 1;                   // K-parity
    const int cp = (wid >> 1) & 1;            // col-pair {2cp, 2cp+1}
    const int rp = wid >> 2;                  // row-tile pair {rp, rp+2}

    // staging constants: thread -> (row, k-quad) and LDS frag slot.
    // Each thread stages BOTH halves (hi and lo).
    const int row_s = tid >> 3;               // 0..63
    const int kq8   = tid & 7;
    const int s_loc = kq8 >> 2, k8 = kq8 & 3;
    // swizzled stage slot: logical slot XOR kq8 (bijective within each
    // 64-slot panel; spreads the 8 same-row lanes across all 8 bank-groups)
    const int slot  = (((s_loc * 4 + (row_s >> 4)) * 64) + k8 * 16 + (row_s & 15)) ^ kq8;
    const int grow  = bm0 + row_s;
    const int kin   = kq8 * 8;

    // stage W-hi slab into LDS once (frag-linear)
    {
        const bf16* whif = layer ? a.W1hif : a.W0hif;
        const bf16* wsrc = whif + (size_t)ng * (size_t)(layer ? 65536 : 49152);
        const int NW = layer ? 16 : 12;
        for (int i = 0; i < NW; ++i) {
            const int ix = i * 512 + tid;
            ((bf16x8*)lds)[ix] = *(const bf16x8*)(wsrc + (size_t)ix * 8);
        }
    }
    __syncthreads();
    const bf16* wlo_blk = (layer ? a.W1lof : a.W0lof)
                          + (size_t)ng * (size_t)(layer ? 65536 : 49152);

    // pointwise ownership: (m, jp..jp+1), 512 threads cover 64 x 8 pairs
    const int m  = (tid >> 3) & 63;
    const int jp = (tid & 7) * 2;
    const int j  = j0 + jp;
    const float* bs = layer ? a.bsum1 : a.bsum0;
    const float bI0 = bs[j],        bI1 = bs[j + 1];
    const float bF0 = bs[512 + j],  bF1 = bs[512 + j + 1];
    const float bG0 = bs[1024 + j], bG1 = bs[1024 + j + 1];
    const float bO0 = bs[1536 + j], bO1 = bs[1536 + j + 1];
    float c0r = 0.f, c1r = 0.f;
    const size_t hix = (size_t)(bm0 + m) * H + j;   // 4B-aligned (j even)

    unsigned int* bar = a.bar + mg * 64;
    constexpr unsigned HB = (unsigned)(B * H * 2);   // state buffer bytes

    if (layer == 0) {
        // own W-lo: parity chunks x 2 S x 2 cols = 24 frags (96 VGPR), once
        bf16x8 wlo_own[24];
#pragma unroll
        for (int cl = 0; cl < 6; ++cl)
#pragma unroll
            for (int s2 = 0; s2 < 2; ++s2)
#pragma unroll
                for (int cc = 0; cc < 2; ++cc) {
                    const int S = (cl * 2 + kh) * 2 + s2;
                    const int col = cp * 2 + cc;
                    wlo_own[(cl * 2 + s2) * 2 + cc] =
                        *(const bf16x8*)(wlo_blk + (size_t)((S * 4 + col) * 64 + lane) * 8);
                }

        for (int t = 0; t <= L; ++t) {
            const int p0 = t & 1;
            if (t < L) {
                const bf16* a0h = a.ehi + (size_t)t * B * P;
                const bf16* a0l = a.elo + (size_t)t * B * P;
                const i32x4 r1h = make_rsrc(a.h0hi[1 - p0], HB);
                const i32x4 r1l = make_rsrc(a.h0lo[1 - p0], HB);
                tick_body<12, 0>(tid, lane, rp, cp, kh, grow, kin, slot,
                                 a0h, a0l, r1h, r1l, lds, wlo_own,
                                 bI0, bI1, bF0, bF1, bG0, bG1, bO0, bO1,
                                 c0r, c1r,
                                 (unsigned int*)(a.h0hi[p0] + hix),
                                 (unsigned int*)(a.h0lo[p0] + hix), m, jp);
            }
            group_bar(bar, t);
        }
    } else {
        // own W-lo: parity chunks x 2 S x 2 cols = 32 frags (128 VGPR), once
        bf16x8 wlo_own[32];
#pragma unroll
        for (int cl = 0; cl < 8; ++cl)
#pragma unroll
            for (int s2 = 0; s2 < 2; ++s2)
#pragma unroll
                for (int cc = 0; cc < 2; ++cc) {
                    const int S = (cl * 2 + kh) * 2 + s2;
                    const int col = cp * 2 + cc;
                    wlo_own[(cl * 2 + s2) * 2 + cc] =
                        *(const bf16x8*)(wlo_blk + (size_t)((S * 4 + col) * 64 + lane) * 8);
                }

        for (int t = 0; t <= L; ++t) {
            const int p0 = t & 1;
            if (t >= 1) {
                // cross-XCD: h0[t-1] (written on XCD mg) via sc1 cload
                const bf16* a0h = a.h0hi[1 - p0];
                const bf16* a0l = a.h0lo[1 - p0];
                // co-XCD: h1[t-2] via sc0
                const i32x4 r1h = make_rsrc(a.h1hi[p0], HB);
                const i32x4 r1l = make_rsrc(a.h1lo[p0], HB);
                tick_body<16, 1>(tid, lane, rp, cp, kh, grow, kin, slot,
                                 a0h, a0l, r1h, r1l, lds, wlo_own,
                                 bI0, bI1, bF0, bF1, bG0, bG1, bO0, bO1,
                                 c0r, c1r,
                                 (unsigned int*)(a.h1hi[1 - p0] + hix),
                                 (unsigned int*)(a.h1lo[1 - p0] + hix), m, jp);
            }
            group_bar(bar, t);
        }
    }
}

// ---------------------------------------------------------------------------
// head: per batch row b, j = joint_index[b]
// ---------------------------------------------------------------------------
__global__ __launch_bounds__(256) void head_kernel(
    const bf16* __restrict__ h_hi, const bf16* __restrict__ h_lo,
    const int* __restrict__ joint_index,
    const float* __restrict__ Wh1, const float* __restrict__ bh1,
    const float* __restrict__ Wh2, const float* __restrict__ bh2,
    float* __restrict__ out)
{
    const int b = blockIdx.x;
    const int t = threadIdx.x;
    const int j = joint_index[b];
    __shared__ float hs[H];
    __shared__ float zs[M];

    hs[t]       = (float)h_hi[(size_t)b * H + t]       + (float)h_lo[(size_t)b * H + t];
    hs[t + 256] = (float)h_hi[(size_t)b * H + 256 + t] + (float)h_lo[(size_t)b * H + 256 + t];
    __syncthreads();

    float acc = bh1[j * M + t];
    const float* w = Wh1 + (size_t)j * H * M + t;
#pragma unroll 8
    for (int k = 0; k < H; ++k) acc = fmaf(hs[k], w[(size_t)k * M], acc);

    zs[t] = gelu_exact(acc);
    __syncthreads();

    if (t < HOR) {
        float a = bh2[j * HOR + t];
        const float* w2 = Wh2 + (size_t)j * M * HOR + t;
        for (int mm = 0; mm < M; ++mm) a = fmaf(zs[mm], w2[(size_t)mm * HOR], a);
        out[(size_t)b * HOR + t] = a;
    }
}

// ---------------------------------------------------------------------------
extern "C" void kernel_launch(void* const* d_in, const int* in_sizes, int n_in,
                              void* d_out, int out_size, void* d_ws, size_t ws_size,
                              hipStream_t stream)
{
    const float* x     = (const float*)d_in[0];
    const int*   joint = (const int*)  d_in[1];
    const float* Wp    = (const float*)d_in[2];
    const float* bp    = (const float*)d_in[3];
    const float* gamma = (const float*)d_in[4];
    const float* beta  = (const float*)d_in[5];
    const float* Wih0  = (const float*)d_in[6];
    const float* Whh0  = (const float*)d_in[7];
    const float* bih0  = (const float*)d_in[8];
    const float* bhh0  = (const float*)d_in[9];
    const float* Wih1  = (const float*)d_in[10];
    const float* Whh1  = (const float*)d_in[11];
    const float* bih1  = (const float*)d_in[12];
    const float* bhh1  = (const float*)d_in[13];
    const float* Wh1   = (const float*)d_in[14];
    const float* bh1   = (const float*)d_in[15];
    const float* Wh2   = (const float*)d_in[16];
    const float* bh2   = (const float*)d_in[17];
    float* out = (float*)d_out;

    char* base = (char*)d_ws;
    size_t off = 0;
    auto take = [&](size_t nbytes) -> void* {
        void* p = base + off;
        off = (off + nbytes + 255) & ~(size_t)255;
        return p;
    };

    RArgs a;
    a.W0hif = (bf16*)take((size_t)G * K0 * 2);
    a.W0lof = (bf16*)take((size_t)G * K0 * 2);
    a.W1hif = (bf16*)take((size_t)G * K1 * 2);
    a.W1lof = (bf16*)take((size_t)G * K1 * 2);
    a.bsum0 = (float*)take(G * 4);
    a.bsum1 = (float*)take(G * 4);

    const size_t states_off = off;
    for (int i = 0; i < 2; ++i) a.h0hi[i] = (bf16*)take((size_t)B * H * 2);
    for (int i = 0; i < 2; ++i) a.h0lo[i] = (bf16*)take((size_t)B * H * 2);
    for (int i = 0; i < 2; ++i) a.h1hi[i] = (bf16*)take((size_t)B * H * 2);
    for (int i = 0; i < 2; ++i) a.h1lo[i] = (bf16*)take((size_t)B * H * 2);
    a.bar = (unsigned int*)take(4 * 256);
    const size_t states_bytes = off - states_off;   // h bufs + bar -> zeroed

    bf16* ehi = (bf16*)take((size_t)L * B * P * 2);
    bf16* elo = (bf16*)take((size_t)L * B * P * 2);
    a.use_elo = (off <= ws_size) ? 1 : 0;
    if (!a.use_elo) elo = ehi;
    a.ehi = ehi; a.elo = elo;

    prep_w_frag<<<dim3(32, K0 / 32, 4), 64, 0, stream>>>(Wih0, Whh0, P,
                                                         (bf16*)a.W0hif, (bf16*)a.W0lof);
    prep_w_frag<<<dim3(32, K1 / 32, 4), 64, 0, stream>>>(Wih1, Whh1, H,
                                                         (bf16*)a.W1hif, (bf16*)a.W1lof);
    prep_bias<<<8, 256, 0, stream>>>(bih0, bhh0, bih1, bhh1,
                                     (float*)a.bsum0, (float*)a.bsum1);
    hipMemsetAsync(base + states_off, 0, states_bytes, stream);
    emb_kernel<<<B * L, 256, 0, stream>>>(x, Wp, bp, gamma, beta, ehi, elo, a.use_elo);

    hipFuncSetAttribute((const void*)recurrence_kernel,
                        hipFuncAttributeMaxDynamicSharedMemorySize, LDS_BYTES);
    void* params[] = { &a };
    hipLaunchCooperativeKernel((void*)recurrence_kernel, dim3(256), dim3(512),
                               params, LDS_BYTES, stream);

    // final h1 (step 511) written at tick t=512 into buf[1-(512&1)] = buf 1
    head_kernel<<<B, 256, 0, stream>>>(a.h1hi[1], a.h1lo[1], joint, Wh1, bh1, Wh2, bh2, out);
}

// Round 12
// 6016.190 us; speedup vs baseline: 1.1980x; 1.1980x over previous
//
#include <hip/hip_runtime.h>
#include <math.h>

typedef __bf16 bf16;
typedef __attribute__((ext_vector_type(8))) __bf16 bf16x8;
typedef __attribute__((ext_vector_type(4))) float f32x4;
typedef __attribute__((ext_vector_type(16))) float f32x16;
typedef __attribute__((ext_vector_type(4))) int i32x4;

// CK-style direct intrinsic binding: buffer load with explicit cache policy.
// cpol=1 -> sc0: bypass L1, served/allocated at L2.
extern "C" __device__ i32x4 llvm_amdgcn_raw_buffer_load_v4i32(
    i32x4 rsrc, int voffset, int soffset, int cpol) __asm("llvm.amdgcn.raw.buffer.load.v4i32");

static constexpr int B = 256, L = 512, D = 64, P = 256, H = 512, M = 256, HOR = 9;
static constexpr int G = 2048;
static constexpr int K0 = P + H;      // 768
static constexpr int K1 = 2 * H;      // 1024
static constexpr float EPS = 1e-5f;
static constexpr int NB = 4;          // rolling A-prefetch depth (chunks)
static constexpr int LDS_BYTES = 163840;   // W-hi(max 128K) + 2x16K A dbuf

#define MFMA32(a, b, c) __builtin_amdgcn_mfma_f32_32x32x16_bf16((a), (b), (c), 0, 0, 0)

__device__ __forceinline__ float sigmoidf_(float x) { return 1.0f / (1.0f + expf(-x)); }
__device__ __forceinline__ float gelu_exact(float x) {
    return 0.5f * x * (1.0f + erff(x * 0.70710678118654752f));
}

// Chunk barrier: publish LDS writes (lgkmcnt only) WITHOUT draining vmcnt.
// sched_barrier pair required (rule #18).
__device__ __forceinline__ void lds_barrier() {
    asm volatile("s_waitcnt lgkmcnt(0)" ::: "memory");
    __builtin_amdgcn_sched_barrier(0);
    __builtin_amdgcn_s_barrier();
    __builtin_amdgcn_sched_barrier(0);
}

// Device-coherent 16B load (2 x 8B agent-scope relaxed atomic loads -> sc1,
// reads past any stale per-XCD L2). For CROSS-XCD state only.
__device__ __forceinline__ bf16x8 cload(const bf16* p) {
    union { unsigned long long u[2]; bf16x8 v; } r;
    const unsigned long long* q = (const unsigned long long*)p;
    r.u[0] = __hip_atomic_load(q,     __ATOMIC_RELAXED, __HIP_MEMORY_SCOPE_AGENT);
    r.u[1] = __hip_atomic_load(q + 1, __ATOMIC_RELAXED, __HIP_MEMORY_SCOPE_AGENT);
    return r.v;
}

// sc0 buffer load: L1-bypass, L2-served. Co-XCD state only (producer's sc1
// write-through leaves local L2 updated-or-absent, never stale — R7-R11
// HW-validated: correct results + FETCH collapse to ~1 MB/tick).
__device__ __forceinline__ i32x4 make_rsrc(const void* p, unsigned bytes) {
    union { const void* p; unsigned u[2]; } a; a.p = p;
    i32x4 r;
    r.x = (int)a.u[0];
    r.y = (int)(a.u[1] & 0xFFFFu);     // base[47:32], stride=0
    r.z = (int)bytes;                  // num_records (bytes, stride==0)
    r.w = 0x00020000;                  // raw untyped dword access
    return r;
}
__device__ __forceinline__ bf16x8 bload_sc0(i32x4 rsrc, int voff) {
    union { i32x4 i; bf16x8 b; } u;
    u.i = llvm_amdgcn_raw_buffer_load_v4i32(rsrc, voff, 0, 1 /*sc0*/);
    return u.b;
}

// ---------------------------------------------------------------------------
// emb = gelu(LN(x@Wp+bp)) -> bf16 hi/lo, T-MAJOR: [(t*B + b)*P + p]
// ---------------------------------------------------------------------------
__global__ __launch_bounds__(256) void emb_kernel(
    const float* __restrict__ x, const float* __restrict__ Wp,
    const float* __restrict__ bp, const float* __restrict__ gamma,
    const float* __restrict__ beta, bf16* __restrict__ ehi,
    bf16* __restrict__ elo, int use_elo)
{
    const int row = blockIdx.x;          // b*L + t
    const int b   = row >> 9;
    const int t   = row & (L - 1);
    const int p   = threadIdx.x;
    __shared__ float xs[D];
    __shared__ float red[P];

    if (p < D) xs[p] = x[(size_t)row * D + p];
    __syncthreads();

    float acc = bp[p];
#pragma unroll
    for (int k = 0; k < D; ++k) acc = fmaf(xs[k], Wp[k * P + p], acc);

    red[p] = acc;
    __syncthreads();
    for (int s = 128; s > 0; s >>= 1) { if (p < s) red[p] += red[p + s]; __syncthreads(); }
    const float mu = red[0] * (1.0f / (float)P);
    __syncthreads();
    const float d = acc - mu;
    red[p] = d * d;
    __syncthreads();
    for (int s = 128; s > 0; s >>= 1) { if (p < s) red[p] += red[p + s]; __syncthreads(); }
    const float var = red[0] * (1.0f / (float)P);

    const float v = gelu_exact(gamma[p] * d * rsqrtf(var + EPS) + beta[p]);
    const size_t o = ((size_t)t * B + b) * P + p;
    const bf16 hh = (bf16)v;
    ehi[o] = hh;
    if (use_elo) elo[o] = (bf16)(v - (float)hh);
}

// ---------------------------------------------------------------------------
// weight prep in FRAG-LINEAR order: for (ng, S, wc, lane):
//   8 bf16 at W[g = wc*512 + ng*16 + (lane&15)][k = S*32 + (lane>>4)*8 ..+8]
// linear index = (((ng*(K/32) + S)*4 + wc)*64 + lane)*8
// ---------------------------------------------------------------------------
__global__ __launch_bounds__(64) void prep_w_frag(
    const float* __restrict__ Wih, const float* __restrict__ Whh, int Kih,
    bf16* __restrict__ hi, bf16* __restrict__ lo)
{
    const int ng = blockIdx.x, S = blockIdx.y, wc = blockIdx.z;
    const int lane = threadIdx.x;
    const int g = wc * 512 + ng * 16 + (lane & 15);
    const int kbase = S * 32 + (lane >> 4) * 8;
    const size_t out = ((((size_t)ng * gridDim.y + S) * 4 + wc) * 64 + lane) * 8;
#pragma unroll
    for (int e = 0; e < 8; ++e) {
        const int k = kbase + e;
        const float v = (k < Kih) ? Wih[(size_t)g * Kih + k]
                                  : Whh[(size_t)g * 512 + (k - Kih)];
        const bf16 h = (bf16)v;
        hi[out + e] = h;
        lo[out + e] = (bf16)(v - (float)h);
    }
}

__global__ __launch_bounds__(256) void prep_bias(
    const float* __restrict__ bih0, const float* __restrict__ bhh0,
    const float* __restrict__ bih1, const float* __restrict__ bhh1,
    float* __restrict__ bsum0, float* __restrict__ bsum1)
{
    const int g = blockIdx.x * 256 + threadIdx.x;   // grid.x = 8
    bsum0[g] = bih0[g] + bhh0[g];
    bsum1[g] = bih1[g] + bhh1[g];
}

// ---------------------------------------------------------------------------
// Persistent recurrence, 256 blocks x 512 THREADS (8 waves, 1 block/CU).
//
// R12: 32x32x16 MFMA. Same operand bytes per MFMA (8 bf16/lane), 2x the
// FLOPs -> HALF the LDS reads per FLOP. Output 64x64 = 2x2 tiles of 32x32;
// wave (rp2, cp2, kh2): tile (rp2,cp2), kh2 = which K=32 half of EVERY
// staged chunk it consumes — all 8 waves active every chunk (R11's parity
// gating idled SIMDs; that was the measured regression). Per wave per
// chunk: 6 b128 reads + 6 MFMA (R9: 10 + 12). W-lo register-resident with
// the SAME frag count as R9 (NC*2 = 24/32), per-lane gather from the
// frag-linear layout. A reads reuse the staged layout + XOR swizzle:
// byte = ((s2*4+rg)*64 + q*16 + l15)*16 ^ ((s2*4+q)<<4), rg=rp2*2+lh4,
// q=ks*2+l5. C/D park: col=lane&31, row=(reg&3)+8*(reg>>2)+4*(lane>>5)
// (guide m74/m101-verified), two-phase kh2 merge (once per tick).
//
// Coherence (R7-R11, HW-validated): no invalidates. State writes sc1
// write-through; co-XCD state reads sc0; cross-XCD reads (L1's h0) sc1;
// immutable data plain. R4 decode: XCD = bid%8 = layer*4+mg producer-pure;
// 64-block group barrier per tick.
// ---------------------------------------------------------------------------
struct RArgs {
    int use_elo;
    const bf16 *ehi, *elo;
    const bf16 *W0hif, *W0lof, *W1hif, *W1lof;   // frag-linear
    const float *bsum0, *bsum1;
    bf16 *h0hi[2], *h0lo[2], *h1hi[2], *h1lo[2];
    unsigned int* bar;    // 4 counters, 256B apart
};

template <int NC, int LAYER>
__device__ __forceinline__ void tick_body(
    int tid, int lane, int rp2, int cp2, int kh2,
    int grow, int kin, int slot,
    const bf16* __restrict__ a0h, const bf16* __restrict__ a0l,
    i32x4 r1h, i32x4 r1l,
    char* lds, const bf16x8* wlo_own,
    float bI0, float bI1, float bF0, float bF1,
    float bG0, float bG1, float bO0, float bO1,
    float& c0r, float& c1r,
    unsigned int* hw_hi, unsigned int* hw_lo,
    int m, int jp)
{
    constexpr int K0seg = (LAYER == 0) ? 256 : 512;
    constexpr int AS0   = (LAYER == 0) ? 256 : 512;

    const bf16* wlds = (const bf16*)lds;
    char* dbuf = lds + 131072;
    float (*Gs)[68] = (float(*)[68])(lds + 131072);

    const int l15 = lane & 15;
    const int lh4 = (lane >> 4) & 1;
    const int l5  = lane >> 5;
    const int rg  = rp2 * 2 + lh4;    // 16-row group of the A fragment
    const int wcw = cp2 * 2 + lh4;    // W fragment wc index (16-col group)

    auto cloadA = [&](int c, int hf) -> bf16x8 {
        const int kk = c * 64 + kin;
        if (kk < K0seg) {
            const bf16* p = (hf ? a0l : a0h) + (size_t)grow * AS0 + kk;
            if (LAYER == 0) return *(const bf16x8*)p;   // emb: immutable, plain
            return cload(p);                            // h0 cross-XCD: sc1
        }
        // co-XCD state (L0: h0; L1: h1) -> sc0 (L2-served, shared on XCD)
        return bload_sc0(hf ? r1l : r1h, ((grow << 9) + (kk - K0seg)) * 2);
    };
    auto stageW = [&](const bf16x8& v, int pb, int hf) {
        *(bf16x8*)(dbuf + pb * 16384 + hf * 8192 + slot * 16) = v;
    };

    f32x16 hh, lh2, hl;
#pragma unroll
    for (int i = 0; i < 16; ++i) { hh[i] = 0.f; lh2[i] = 0.f; hl[i] = 0.f; }

    // rolling A prefetch (NB chunks deep, both halves per thread)
    bf16x8 aregH[NB], aregL[NB];
#pragma unroll
    for (int i = 0; i < NB; ++i) { aregH[i] = cloadA(i, 0); aregL[i] = cloadA(i, 1); }
    stageW(aregH[0], 0, 0);
    stageW(aregL[0], 0, 1);
    aregH[0] = cloadA(NB, 0);
    aregL[0] = cloadA(NB, 1);
    lds_barrier();

#pragma unroll
    for (int c = 0; c < NC; ++c) {
        if (c + 1 < NC) {
            stageW(aregH[(c + 1) % NB], (c + 1) & 1, 0);
            stageW(aregL[(c + 1) % NB], (c + 1) & 1, 1);
            if (c + 1 + NB < NC) {
                aregH[(c + 1) % NB] = cloadA(c + 1 + NB, 0);
                aregL[(c + 1) % NB] = cloadA(c + 1 + NB, 1);
            }
        }
        const char* bufc = dbuf + (c & 1) * 16384;
        const int Sg = c * 2 + kh2;          // global weight S (K=32 slice)
#pragma unroll
        for (int ks = 0; ks < 2; ++ks) {     // two K=16 steps of this half
            const int q = ks * 2 + l5;       // k-quad index within S
            const int ofsA = (((kh2 * 4 + rg) * 64 + q * 16 + l15) * 16)
                             ^ ((kh2 * 4 + q) << 4);
            bf16x8 Ahi = *(const bf16x8*)(bufc + ofsA);
            bf16x8 Alo = *(const bf16x8*)(bufc + 8192 + ofsA);
            bf16x8 Whi = *(const bf16x8*)((const char*)wlds
                           + ((Sg * 4 + wcw) * 64 + q * 16 + l15) * 16);
            const bf16x8 Wlo = wlo_own[c * 2 + ks];   // register, static idx
            hh  = MFMA32(Ahi, Whi, hh);
            lh2 = MFMA32(Alo, Whi, lh2);
            hl  = MFMA32(Ahi, Wlo, hl);
        }
        lds_barrier();   // publish next stage; vmem prefetch stays in flight
    }

    // two-phase park (32x32 C/D: col=lane&31, row=(reg&3)+8*(reg>>2)+4*l5)
    if (kh2 == 0) {
#pragma unroll
        for (int reg = 0; reg < 16; ++reg) {
            const int row = rp2 * 32 + (reg & 3) + 8 * (reg >> 2) + 4 * l5;
            const int col = cp2 * 32 + (lane & 31);
            Gs[row][col] = hh[reg] + lh2[reg] + hl[reg];
        }
    }
    lds_barrier();
    if (kh2 == 1) {
#pragma unroll
        for (int reg = 0; reg < 16; ++reg) {
            const int row = rp2 * 32 + (reg & 3) + 8 * (reg >> 2) + 4 * l5;
            const int col = cp2 * 32 + (lane & 31);
            Gs[row][col] += hh[reg] + lh2[reg] + hl[reg];
        }
    }
    lds_barrier();

    // pointwise: all 512 threads, (m, jp..jp+1)
    {
        float hv0, hv1;
        {
            const float iraw = Gs[m][jp]      + bI0;
            const float fraw = Gs[m][16 + jp] + bF0;
            const float graw = Gs[m][32 + jp] + bG0;
            const float oraw = Gs[m][48 + jp] + bO0;
            const float cv = sigmoidf_(fraw) * c0r + sigmoidf_(iraw) * tanhf(graw);
            c0r = cv;
            hv0 = sigmoidf_(oraw) * tanhf(cv);
        }
        {
            const float iraw = Gs[m][jp + 1]      + bI1;
            const float fraw = Gs[m][16 + jp + 1] + bF1;
            const float graw = Gs[m][32 + jp + 1] + bG1;
            const float oraw = Gs[m][48 + jp + 1] + bO1;
            const float cv = sigmoidf_(fraw) * c1r + sigmoidf_(iraw) * tanhf(graw);
            c1r = cv;
            hv1 = sigmoidf_(oraw) * tanhf(cv);
        }
        union { unsigned int u; bf16 b[2]; } ph, pl;
        ph.b[0] = (bf16)hv0; ph.b[1] = (bf16)hv1;
        pl.b[0] = (bf16)(hv0 - (float)ph.b[0]);
        pl.b[1] = (bf16)(hv1 - (float)ph.b[1]);
        // agent-scope write-through: LLC-visible once vmcnt drains; local L2
        // left updated-or-absent (never stale) for next tick's sc0 readers.
        __hip_atomic_store(hw_hi, ph.u, __ATOMIC_RELAXED, __HIP_MEMORY_SCOPE_AGENT);
        __hip_atomic_store(hw_lo, pl.u, __ATOMIC_RELAXED, __HIP_MEMORY_SCOPE_AGENT);
    }
}

// group barrier: 64 blocks of row-group mg (XCD mg + XCD 4+mg). No cache
// maintenance — scope-precise loads make it unnecessary (R7-R11-validated).
__device__ __forceinline__ void group_bar(unsigned int* bar, int t) {
    __syncthreads();   // drains vmcnt -> agent stores visible at LLC
    if (threadIdx.x == 0) {
        __hip_atomic_fetch_add(bar, 1u, __ATOMIC_RELAXED, __HIP_MEMORY_SCOPE_AGENT);
        const unsigned int target = 64u * (unsigned)(t + 1);
        while (__hip_atomic_load(bar, __ATOMIC_RELAXED, __HIP_MEMORY_SCOPE_AGENT) < target)
            __builtin_amdgcn_s_sleep(1);
        __builtin_amdgcn_fence(__ATOMIC_ACQUIRE, "workgroup");
    }
    __syncthreads();
}

__global__ __launch_bounds__(512, 1) void recurrence_kernel(RArgs a)
{
    extern __shared__ __align__(16) char lds[];

    // R4 decode: XCD = bid%8 = layer*4+mg (producer-pure per XCD); all 32
    // ng-blocks of one (layer,mg) are co-XCD and time-aligned.
    const int bid   = blockIdx.x;
    const int layer = (bid >> 2) & 1;
    const int mg    = bid & 3;
    const int ng    = bid >> 3;
    const int bm0 = mg * 64, j0 = ng * 16;

    const int tid  = threadIdx.x;            // 0..511
    const int lane = tid & 63;
    const int wid  = tid >> 6;                // 0..7
    const int kh2 = wid & 1;                  // K=32 half of each chunk
    const int cp2 = (wid >> 1) & 1;           // 32-col tile
    const int rp2 = wid >> 2;                 // 32-row tile

    // staging constants: thread -> (row, k-quad) and LDS frag slot.
    // Each thread stages BOTH halves (hi and lo). UNCHANGED from R9.
    const int row_s = tid >> 3;               // 0..63
    const int kq8   = tid & 7;
    const int s_loc = kq8 >> 2, k8 = kq8 & 3;
    // swizzled stage slot: logical slot XOR kq8 (bijective within each
    // 64-slot panel; spreads the 8 same-row lanes across all 8 bank-groups)
    const int slot  = (((s_loc * 4 + (row_s >> 4)) * 64) + k8 * 16 + (row_s & 15)) ^ kq8;
    const int grow  = bm0 + row_s;
    const int kin   = kq8 * 8;

    // stage W-hi slab into LDS once (frag-linear)
    {
        const bf16* whif = layer ? a.W1hif : a.W0hif;
        const bf16* wsrc = whif + (size_t)ng * (size_t)(layer ? 65536 : 49152);
        const int NW = layer ? 16 : 12;
        for (int i = 0; i < NW; ++i) {
            const int ix = i * 512 + tid;
            ((bf16x8*)lds)[ix] = *(const bf16x8*)(wsrc + (size_t)ix * 8);
        }
    }
    __syncthreads();
    const bf16* wlo_blk = (layer ? a.W1lof : a.W0lof)
                          + (size_t)ng * (size_t)(layer ? 65536 : 49152);

    // W-lo gather constants (32-col B fragment built from 16-col frag-linear)
    const int l15 = lane & 15, lh4 = (lane >> 4) & 1, l5 = lane >> 5;
    const int wcw = cp2 * 2 + lh4;

    // pointwise ownership: (m, jp..jp+1), 512 threads cover 64 x 8 pairs
    const int m  = (tid >> 3) & 63;
    const int jp = (tid & 7) * 2;
    const int j  = j0 + jp;
    const float* bs = layer ? a.bsum1 : a.bsum0;
    const float bI0 = bs[j],        bI1 = bs[j + 1];
    const float bF0 = bs[512 + j],  bF1 = bs[512 + j + 1];
    const float bG0 = bs[1024 + j], bG1 = bs[1024 + j + 1];
    const float bO0 = bs[1536 + j], bO1 = bs[1536 + j + 1];
    float c0r = 0.f, c1r = 0.f;
    const size_t hix = (size_t)(bm0 + m) * H + j;   // 4B-aligned (j even)

    unsigned int* bar = a.bar + mg * 64;
    constexpr unsigned HB = (unsigned)(B * H * 2);   // state buffer bytes

    if (layer == 0) {
        // own W-lo: 12 chunks x 2 ks = 24 frags (96 VGPR), loaded once
        bf16x8 wlo_own[24];
#pragma unroll
        for (int cl = 0; cl < 12; ++cl)
#pragma unroll
            for (int ks = 0; ks < 2; ++ks) {
                const int S = cl * 2 + kh2;
                const int q = ks * 2 + l5;
                wlo_own[cl * 2 + ks] = *(const bf16x8*)(
                    wlo_blk + (size_t)((S * 4 + wcw) * 64 + q * 16 + l15) * 8);
            }

        for (int t = 0; t <= L; ++t) {
            const int p0 = t & 1;
            if (t < L) {
                const bf16* a0h = a.ehi + (size_t)t * B * P;
                const bf16* a0l = a.elo + (size_t)t * B * P;
                const i32x4 r1h = make_rsrc(a.h0hi[1 - p0], HB);
                const i32x4 r1l = make_rsrc(a.h0lo[1 - p0], HB);
                tick_body<12, 0>(tid, lane, rp2, cp2, kh2, grow, kin, slot,
                                 a0h, a0l, r1h, r1l, lds, wlo_own,
                                 bI0, bI1, bF0, bF1, bG0, bG1, bO0, bO1,
                                 c0r, c1r,
                                 (unsigned int*)(a.h0hi[p0] + hix),
                                 (unsigned int*)(a.h0lo[p0] + hix), m, jp);
            }
            group_bar(bar, t);
        }
    } else {
        // own W-lo: 16 chunks x 2 ks = 32 frags (128 VGPR), loaded once
        bf16x8 wlo_own[32];
#pragma unroll
        for (int cl = 0; cl < 16; ++cl)
#pragma unroll
            for (int ks = 0; ks < 2; ++ks) {
                const int S = cl * 2 + kh2;
                const int q = ks * 2 + l5;
                wlo_own[cl * 2 + ks] = *(const bf16x8*)(
                    wlo_blk + (size_t)((S * 4 + wcw) * 64 + q * 16 + l15) * 8);
            }

        for (int t = 0; t <= L; ++t) {
            const int p0 = t & 1;
            if (t >= 1) {
                // cross-XCD: h0[t-1] (written on XCD mg) via sc1 cload
                const bf16* a0h = a.h0hi[1 - p0];
                const bf16* a0l = a.h0lo[1 - p0];
                // co-XCD: h1[t-2] via sc0
                const i32x4 r1h = make_rsrc(a.h1hi[p0], HB);
                const i32x4 r1l = make_rsrc(a.h1lo[p0], HB);
                tick_body<16, 1>(tid, lane, rp2, cp2, kh2, grow, kin, slot,
                                 a0h, a0l, r1h, r1l, lds, wlo_own,
                                 bI0, bI1, bF0, bF1, bG0, bG1, bO0, bO1,
                                 c0r, c1r,
                                 (unsigned int*)(a.h1hi[1 - p0] + hix),
                                 (unsigned int*)(a.h1lo[1 - p0] + hix), m, jp);
            }
            group_bar(bar, t);
        }
    }
}

// ---------------------------------------------------------------------------
// head: per batch row b, j = joint_index[b]
// ---------------------------------------------------------------------------
__global__ __launch_bounds__(256) void head_kernel(
    const bf16* __restrict__ h_hi, const bf16* __restrict__ h_lo,
    const int* __restrict__ joint_index,
    const float* __restrict__ Wh1, const float* __restrict__ bh1,
    const float* __restrict__ Wh2, const float* __restrict__ bh2,
    float* __restrict__ out)
{
    const int b = blockIdx.x;
    const int t = threadIdx.x;
    const int j = joint_index[b];
    __shared__ float hs[H];
    __shared__ float zs[M];

    hs[t]       = (float)h_hi[(size_t)b * H + t]       + (float)h_lo[(size_t)b * H + t];
    hs[t + 256] = (float)h_hi[(size_t)b * H + 256 + t] + (float)h_lo[(size_t)b * H + 256 + t];
    __syncthreads();

    float acc = bh1[j * M + t];
    const float* w = Wh1 + (size_t)j * H * M + t;
#pragma unroll 8
    for (int k = 0; k < H; ++k) acc = fmaf(hs[k], w[(size_t)k * M], acc);

    zs[t] = gelu_exact(acc);
    __syncthreads();

    if (t < HOR) {
        float a = bh2[j * HOR + t];
        const float* w2 = Wh2 + (size_t)j * M * HOR + t;
        for (int mm = 0; mm < M; ++mm) a = fmaf(zs[mm], w2[(size_t)mm * HOR], a);
        out[(size_t)b * HOR + t] = a;
    }
}

// ---------------------------------------------------------------------------
extern "C" void kernel_launch(void* const* d_in, const int* in_sizes, int n_in,
                              void* d_out, int out_size, void* d_ws, size_t ws_size,
                              hipStream_t stream)
{
    const float* x     = (const float*)d_in[0];
    const int*   joint = (const int*)  d_in[1];
    const float* Wp    = (const float*)d_in[2];
    const float* bp    = (const float*)d_in[3];
    const float* gamma = (const float*)d_in[4];
    const float* beta  = (const float*)d_in[5];
    const float* Wih0  = (const float*)d_in[6];
    const float* Whh0  = (const float*)d_in[7];
    const float* bih0  = (const float*)d_in[8];
    const float* bhh0  = (const float*)d_in[9];
    const float* Wih1  = (const float*)d_in[10];
    const float* Whh1  = (const float*)d_in[11];
    const float* bih1  = (const float*)d_in[12];
    const float* bhh1  = (const float*)d_in[13];
    const float* Wh1   = (const float*)d_in[14];
    const float* bh1   = (const float*)d_in[15];
    const float* Wh2   = (const float*)d_in[16];
    const float* bh2   = (const float*)d_in[17];
    float* out = (float*)d_out;

    char* base = (char*)d_ws;
    size_t off = 0;
    auto take = [&](size_t nbytes) -> void* {
        void* p = base + off;
        off = (off + nbytes + 255) & ~(size_t)255;
        return p;
    };

    RArgs a;
    a.W0hif = (bf16*)take((size_t)G * K0 * 2);
    a.W0lof = (bf16*)take((size_t)G * K0 * 2);
    a.W1hif = (bf16*)take((size_t)G * K1 * 2);
    a.W1lof = (bf16*)take((size_t)G * K1 * 2);
    a.bsum0 = (float*)take(G * 4);
    a.bsum1 = (float*)take(G * 4);

    const size_t states_off = off;
    for (int i = 0; i < 2; ++i) a.h0hi[i] = (bf16*)take((size_t)B * H * 2);
    for (int i = 0; i < 2; ++i) a.h0lo[i] = (bf16*)take((size_t)B * H * 2);
    for (int i = 0; i < 2; ++i) a.h1hi[i] = (bf16*)take((size_t)B * H * 2);
    for (int i = 0; i < 2; ++i) a.h1lo[i] = (bf16*)take((size_t)B * H * 2);
    a.bar = (unsigned int*)take(4 * 256);
    const size_t states_bytes = off - states_off;   // h bufs + bar -> zeroed

    bf16* ehi = (bf16*)take((size_t)L * B * P * 2);
    bf16* elo = (bf16*)take((size_t)L * B * P * 2);
    a.use_elo = (off <= ws_size) ? 1 : 0;
    if (!a.use_elo) elo = ehi;
    a.ehi = ehi; a.elo = elo;

    prep_w_frag<<<dim3(32, K0 / 32, 4), 64, 0, stream>>>(Wih0, Whh0, P,
                                                         (bf16*)a.W0hif, (bf16*)a.W0lof);
    prep_w_frag<<<dim3(32, K1 / 32, 4), 64, 0, stream>>>(Wih1, Whh1, H,
                                                         (bf16*)a.W1hif, (bf16*)a.W1lof);
    prep_bias<<<8, 256, 0, stream>>>(bih0, bhh0, bih1, bhh1,
                                     (float*)a.bsum0, (float*)a.bsum1);
    hipMemsetAsync(base + states_off, 0, states_bytes, stream);
    emb_kernel<<<B * L, 256, 0, stream>>>(x, Wp, bp, gamma, beta, ehi, elo, a.use_elo);

    hipFuncSetAttribute((const void*)recurrence_kernel,
                        hipFuncAttributeMaxDynamicSharedMemorySize, LDS_BYTES);
    void* params[] = { &a };
    hipLaunchCooperativeKernel((void*)recurrence_kernel, dim3(256), dim3(512),
                               params, LDS_BYTES, stream);

    // final h1 (step 511) written at tick t=512 into buf[1-(512&1)] = buf 1
    head_kernel<<<B, 256, 0, stream>>>(a.h1hi[1], a.h1lo[1], joint, Wh1, bh1, Wh2, bh2, out);
}

// Round 13
// 4819.582 us; speedup vs baseline: 1.4954x; 1.2483x over previous
//
#include <hip/hip_runtime.h>
#include <math.h>

typedef __bf16 bf16;
typedef __attribute__((ext_vector_type(8))) __bf16 bf16x8;
typedef __attribute__((ext_vector_type(4))) float f32x4;
typedef __attribute__((ext_vector_type(4))) int i32x4;

// CK-style direct intrinsic binding: buffer load with explicit cache policy.
// cpol=1 -> sc0: bypass L1, served/allocated at L2.
extern "C" __device__ i32x4 llvm_amdgcn_raw_buffer_load_v4i32(
    i32x4 rsrc, int voffset, int soffset, int cpol) __asm("llvm.amdgcn.raw.buffer.load.v4i32");

static constexpr int B = 256, L = 512, D = 64, P = 256, H = 512, M = 256, HOR = 9;
static constexpr int G = 2048;
static constexpr int K0 = P + H;      // 768
static constexpr int K1 = 2 * H;      // 1024
static constexpr float EPS = 1e-5f;
static constexpr int NB = 4;          // rolling A-prefetch depth (chunks)
static constexpr int LDS_BYTES = 163840;   // W-hi(max 128K) + 2x16K A dbuf

#define MFMA(a, b, c) __builtin_amdgcn_mfma_f32_16x16x32_bf16((a), (b), (c), 0, 0, 0)

__device__ __forceinline__ float sigmoidf_(float x) { return 1.0f / (1.0f + expf(-x)); }
__device__ __forceinline__ float gelu_exact(float x) {
    return 0.5f * x * (1.0f + erff(x * 0.70710678118654752f));
}

// Chunk barrier: publish LDS writes (lgkmcnt only) WITHOUT draining vmcnt.
// sched_barrier pair required (rule #18).
__device__ __forceinline__ void lds_barrier() {
    asm volatile("s_waitcnt lgkmcnt(0)" ::: "memory");
    __builtin_amdgcn_sched_barrier(0);
    __builtin_amdgcn_s_barrier();
    __builtin_amdgcn_sched_barrier(0);
}

// Device-coherent 16B load (2 x 8B agent-scope relaxed atomic loads -> sc1,
// reads past any stale per-XCD L2). For CROSS-XCD state only.
__device__ __forceinline__ bf16x8 cload(const bf16* p) {
    union { unsigned long long u[2]; bf16x8 v; } r;
    const unsigned long long* q = (const unsigned long long*)p;
    r.u[0] = __hip_atomic_load(q,     __ATOMIC_RELAXED, __HIP_MEMORY_SCOPE_AGENT);
    r.u[1] = __hip_atomic_load(q + 1, __ATOMIC_RELAXED, __HIP_MEMORY_SCOPE_AGENT);
    return r.v;
}

// sc0 buffer load: L1-bypass, L2-served. Co-XCD state only (producer's sc1
// write-through leaves local L2 updated-or-absent, never stale — R7-R12
// HW-validated: correct results + FETCH collapse to ~1 MB/tick).
__device__ __forceinline__ i32x4 make_rsrc(const void* p, unsigned bytes) {
    union { const void* p; unsigned u[2]; } a; a.p = p;
    i32x4 r;
    r.x = (int)a.u[0];
    r.y = (int)(a.u[1] & 0xFFFFu);     // base[47:32], stride=0
    r.z = (int)bytes;                  // num_records (bytes, stride==0)
    r.w = 0x00020000;                  // raw untyped dword access
    return r;
}
__device__ __forceinline__ bf16x8 bload_sc0(i32x4 rsrc, int voff) {
    union { i32x4 i; bf16x8 b; } u;
    u.i = llvm_amdgcn_raw_buffer_load_v4i32(rsrc, voff, 0, 1 /*sc0*/);
    return u.b;
}

// ---------------------------------------------------------------------------
// emb = gelu(LN(x@Wp+bp)) -> bf16 hi/lo, T-MAJOR: [(t*B + b)*P + p]
// ---------------------------------------------------------------------------
__global__ __launch_bounds__(256) void emb_kernel(
    const float* __restrict__ x, const float* __restrict__ Wp,
    const float* __restrict__ bp, const float* __restrict__ gamma,
    const float* __restrict__ beta, bf16* __restrict__ ehi,
    bf16* __restrict__ elo, int use_elo)
{
    const int row = blockIdx.x;          // b*L + t
    const int b   = row >> 9;
    const int t   = row & (L - 1);
    const int p   = threadIdx.x;
    __shared__ float xs[D];
    __shared__ float red[P];

    if (p < D) xs[p] = x[(size_t)row * D + p];
    __syncthreads();

    float acc = bp[p];
#pragma unroll
    for (int k = 0; k < D; ++k) acc = fmaf(xs[k], Wp[k * P + p], acc);

    red[p] = acc;
    __syncthreads();
    for (int s = 128; s > 0; s >>= 1) { if (p < s) red[p] += red[p + s]; __syncthreads(); }
    const float mu = red[0] * (1.0f / (float)P);
    __syncthreads();
    const float d = acc - mu;
    red[p] = d * d;
    __syncthreads();
    for (int s = 128; s > 0; s >>= 1) { if (p < s) red[p] += red[p + s]; __syncthreads(); }
    const float var = red[0] * (1.0f / (float)P);

    const float v = gelu_exact(gamma[p] * d * rsqrtf(var + EPS) + beta[p]);
    const size_t o = ((size_t)t * B + b) * P + p;
    const bf16 hh = (bf16)v;
    ehi[o] = hh;
    if (use_elo) elo[o] = (bf16)(v - (float)hh);
}

// ---------------------------------------------------------------------------
// weight prep in FRAG-LINEAR order: for (ng, S, wc, lane):
//   8 bf16 at W[g = wc*512 + ng*16 + (lane&15)][k = S*32 + (lane>>4)*8 ..+8]
// linear index = (((ng*(K/32) + S)*4 + wc)*64 + lane)*8
// ---------------------------------------------------------------------------
__global__ __launch_bounds__(64) void prep_w_frag(
    const float* __restrict__ Wih, const float* __restrict__ Whh, int Kih,
    bf16* __restrict__ hi, bf16* __restrict__ lo)
{
    const int ng = blockIdx.x, S = blockIdx.y, wc = blockIdx.z;
    const int lane = threadIdx.x;
    const int g = wc * 512 + ng * 16 + (lane & 15);
    const int kbase = S * 32 + (lane >> 4) * 8;
    const size_t out = ((((size_t)ng * gridDim.y + S) * 4 + wc) * 64 + lane) * 8;
#pragma unroll
    for (int e = 0; e < 8; ++e) {
        const int k = kbase + e;
        const float v = (k < Kih) ? Wih[(size_t)g * Kih + k]
                                  : Whh[(size_t)g * 512 + (k - Kih)];
        const bf16 h = (bf16)v;
        hi[out + e] = h;
        lo[out + e] = (bf16)(v - (float)h);
    }
}

__global__ __launch_bounds__(256) void prep_bias(
    const float* __restrict__ bih0, const float* __restrict__ bhh0,
    const float* __restrict__ bih1, const float* __restrict__ bhh1,
    float* __restrict__ bsum0, float* __restrict__ bsum1)
{
    const int g = blockIdx.x * 256 + threadIdx.x;   // grid.x = 8
    bsum0[g] = bih0[g] + bhh0[g];
    bsum1[g] = bih1[g] + bhh1[g];
}

// ---------------------------------------------------------------------------
// Persistent recurrence, 256 blocks x 512 THREADS (8 waves, 1 block/CU).
// R9 champion structure (5.09 ms; 16x16 MFMA, wave = 2 row-tiles x 1 col,
// W-lo column in registers, balanced waves) — R11/R12 falsified the
// "LDS-read-throughput floor": cutting reads 40% hurt both times. The
// remaining exposed cost is the TICK-BOUNDARY sc1 latency on L1's h0.
//
// R13: L1 chunk REORDER (uniform across blocks): process h1 chunks (8..15,
// co-XCD sc0 ~200cy, published at the t-1 barrier) FIRST, h0 chunks (0..7,
// cross-XCD sc1 ~600-900cy) LAST. h0 loads are issued >=4 phases (~2.5us)
// before consumption -> sc1 latency fully hidden; the tick-prologue stage
// stall drops from ~900cy (sc1) to ~200cy (sc0). Uniform order keeps the
// 32 co-XCD sharers temporally aligned (R6's per-block rotation destroyed
// alignment; this does not). Accumulation order-independent; all weight
// indices stay compile-time (rule #20).
//
// Coherence (R7-R12, HW-validated): no invalidates. State writes sc1
// write-through; co-XCD state reads sc0; cross-XCD reads (L1's h0) sc1;
// immutable data plain. R4 decode: XCD = bid%8 = layer*4+mg producer-pure;
// 64-block group barrier per tick.
// ---------------------------------------------------------------------------
struct RArgs {
    int use_elo;
    const bf16 *ehi, *elo;
    const bf16 *W0hif, *W0lof, *W1hif, *W1lof;   // frag-linear
    const float *bsum0, *bsum1;
    bf16 *h0hi[2], *h0lo[2], *h1hi[2], *h1lo[2];
    unsigned int* bar;    // 4 counters, 256B apart
};

template <int NC, int LAYER>
__device__ __forceinline__ void tick_body(
    int tid, int lane, int wr2, int wc,
    int grow, int kin, int slot,
    const bf16* __restrict__ a0h, const bf16* __restrict__ a0l,
    i32x4 r1h, i32x4 r1l,
    char* lds, const bf16x8* wlo_own,
    float bI0, float bI1, float bF0, float bF1,
    float bG0, float bG1, float bO0, float bO1,
    float& c0r, float& c1r,
    unsigned int* hw_hi, unsigned int* hw_lo,
    int m, int jp)
{
    constexpr int K0seg = (LAYER == 0) ? 256 : 512;
    constexpr int AS0   = (LAYER == 0) ? 256 : 512;

    const bf16* wlds = (const bf16*)lds;
    char* dbuf = lds + 131072;
    float (*Gs)[68] = (float(*)[68])(lds + 131072);

    // phase -> chunk order: L1 consumes h1 (sc0, fast) first, h0 (sc1) last.
    auto ord = [](int p) -> int { return (LAYER == 1) ? ((p + 8) & 15) : p; };

    auto cloadA = [&](int c, int hf) -> bf16x8 {
        const int kk = c * 64 + kin;
        if (kk < K0seg) {
            const bf16* p = (hf ? a0l : a0h) + (size_t)grow * AS0 + kk;
            if (LAYER == 0) return *(const bf16x8*)p;   // emb: immutable, plain
            return cload(p);                            // h0 cross-XCD: sc1
        }
        // co-XCD state (L0: h0; L1: h1) -> sc0 (L2-served, shared on XCD)
        return bload_sc0(hf ? r1l : r1h, ((grow << 9) + (kk - K0seg)) * 2);
    };
    auto stageW = [&](const bf16x8& v, int pb, int hf) {
        *(bf16x8*)(dbuf + pb * 16384 + hf * 8192 + slot * 16) = v;
    };

    f32x4 hh[2], lh[2], hl[2];
#pragma unroll
    for (int i = 0; i < 2; ++i) {
        hh[i] = f32x4{0.f,0.f,0.f,0.f};
        lh[i] = f32x4{0.f,0.f,0.f,0.f};
        hl[i] = f32x4{0.f,0.f,0.f,0.f};
    }

    // rolling A prefetch (NB phases deep, both halves per thread)
    bf16x8 aregH[NB], aregL[NB];
#pragma unroll
    for (int i = 0; i < NB; ++i) { aregH[i] = cloadA(ord(i), 0); aregL[i] = cloadA(ord(i), 1); }
    stageW(aregH[0], 0, 0);
    stageW(aregL[0], 0, 1);
    aregH[0] = cloadA(ord(NB), 0);
    aregL[0] = cloadA(ord(NB), 1);
    lds_barrier();

#pragma unroll
    for (int c = 0; c < NC; ++c) {
        const int cr = ord(c);               // chunk processed this phase
        if (c + 1 < NC) {
            stageW(aregH[(c + 1) % NB], (c + 1) & 1, 0);
            stageW(aregL[(c + 1) % NB], (c + 1) & 1, 1);
            if (c + 1 + NB < NC) {
                aregH[(c + 1) % NB] = cloadA(ord(c + 1 + NB), 0);
                aregL[(c + 1) % NB] = cloadA(ord(c + 1 + NB), 1);
            }
        }
        const char* bufc = dbuf + (c & 1) * 16384;
#pragma unroll
        for (int s2 = 0; s2 < 2; ++s2) {
            const int S = cr * 2 + s2;       // global weight S (compile-time)
            const int swz = ((s2 * 4) + (lane >> 4)) << 4;
            bf16x8 Whi = *(const bf16x8*)((const char*)wlds + ((S * 4 + wc) * 64 + lane) * 16);
            const bf16x8 Wlo = wlo_own[S];   // register-resident, static index
#pragma unroll
            for (int rt = 0; rt < 2; ++rt) {
                const int row_tile = wr2 + rt * 2;
                const int ofsA = (((s2 * 4 + row_tile) * 64 + lane) * 16) ^ swz;
                bf16x8 Ahi = *(const bf16x8*)(bufc + ofsA);
                bf16x8 Alo = *(const bf16x8*)(bufc + 8192 + ofsA);
                hh[rt] = MFMA(Ahi, Whi, hh[rt]);
                lh[rt] = MFMA(Alo, Whi, lh[rt]);
                hl[rt] = MFMA(Ahi, Wlo, hl[rt]);
            }
        }
        lds_barrier();   // publish next stage; vmem prefetch stays in flight
    }

    // park gates in Gs (each cell written by exactly one thread)
#pragma unroll
    for (int rt = 0; rt < 2; ++rt) {
        const int row_tile = wr2 + rt * 2;
#pragma unroll
        for (int r = 0; r < 4; ++r) {
            const int row = row_tile * 16 + (lane >> 4) * 4 + r;
            const int col = wc * 16 + (lane & 15);
            Gs[row][col] = hh[rt][r] + lh[rt][r] + hl[rt][r];
        }
    }
    lds_barrier();

    // pointwise: all 512 threads, (m, jp..jp+1)
    {
        float hv0, hv1;
        {
            const float iraw = Gs[m][jp]      + bI0;
            const float fraw = Gs[m][16 + jp] + bF0;
            const float graw = Gs[m][32 + jp] + bG0;
            const float oraw = Gs[m][48 + jp] + bO0;
            const float cv = sigmoidf_(fraw) * c0r + sigmoidf_(iraw) * tanhf(graw);
            c0r = cv;
            hv0 = sigmoidf_(oraw) * tanhf(cv);
        }
        {
            const float iraw = Gs[m][jp + 1]      + bI1;
            const float fraw = Gs[m][16 + jp + 1] + bF1;
            const float graw = Gs[m][32 + jp + 1] + bG1;
            const float oraw = Gs[m][48 + jp + 1] + bO1;
            const float cv = sigmoidf_(fraw) * c1r + sigmoidf_(iraw) * tanhf(graw);
            c1r = cv;
            hv1 = sigmoidf_(oraw) * tanhf(cv);
        }
        union { unsigned int u; bf16 b[2]; } ph, pl;
        ph.b[0] = (bf16)hv0; ph.b[1] = (bf16)hv1;
        pl.b[0] = (bf16)(hv0 - (float)ph.b[0]);
        pl.b[1] = (bf16)(hv1 - (float)ph.b[1]);
        // agent-scope write-through: LLC-visible once vmcnt drains; local L2
        // left updated-or-absent (never stale) for next tick's sc0 readers.
        __hip_atomic_store(hw_hi, ph.u, __ATOMIC_RELAXED, __HIP_MEMORY_SCOPE_AGENT);
        __hip_atomic_store(hw_lo, pl.u, __ATOMIC_RELAXED, __HIP_MEMORY_SCOPE_AGENT);
    }
}

// group barrier: 64 blocks of row-group mg (XCD mg + XCD 4+mg). No cache
// maintenance — scope-precise loads make it unnecessary (R7-R12-validated).
__device__ __forceinline__ void group_bar(unsigned int* bar, int t) {
    __syncthreads();   // drains vmcnt -> agent stores visible at LLC
    if (threadIdx.x == 0) {
        __hip_atomic_fetch_add(bar, 1u, __ATOMIC_RELAXED, __HIP_MEMORY_SCOPE_AGENT);
        const unsigned int target = 64u * (unsigned)(t + 1);
        while (__hip_atomic_load(bar, __ATOMIC_RELAXED, __HIP_MEMORY_SCOPE_AGENT) < target)
            __builtin_amdgcn_s_sleep(1);
        __builtin_amdgcn_fence(__ATOMIC_ACQUIRE, "workgroup");
    }
    __syncthreads();
}

__global__ __launch_bounds__(512, 2) void recurrence_kernel(RArgs a)
{
    extern __shared__ __align__(16) char lds[];

    // R4 decode: XCD = bid%8 = layer*4+mg (producer-pure per XCD); all 32
    // ng-blocks of one (layer,mg) are co-XCD and time-aligned.
    const int bid   = blockIdx.x;
    const int layer = (bid >> 2) & 1;
    const int mg    = bid & 3;
    const int ng    = bid >> 3;
    const int bm0 = mg * 64, j0 = ng * 16;

    const int tid  = threadIdx.x;            // 0..511
    const int lane = tid & 63;
    const int wid  = tid >> 6;                // 0..7
    const int wr2 = wid >> 2, wc = wid & 3;   // row-tile pair {wr2, wr2+2}

    // staging constants: thread -> (row, k-quad) and LDS frag slot.
    // Each thread stages BOTH halves (hi and lo).
    const int row_s = tid >> 3;               // 0..63
    const int kq8   = tid & 7;
    const int s_loc = kq8 >> 2, k8 = kq8 & 3;
    // swizzled stage slot: logical slot XOR kq8 (bijective within each
    // 64-slot panel; spreads the 8 same-row lanes across all 8 bank-groups)
    const int slot  = (((s_loc * 4 + (row_s >> 4)) * 64) + k8 * 16 + (row_s & 15)) ^ kq8;
    const int grow  = bm0 + row_s;
    const int kin   = kq8 * 8;

    // stage W-hi slab into LDS once (frag-linear)
    {
        const bf16* whif = layer ? a.W1hif : a.W0hif;
        const bf16* wsrc = whif + (size_t)ng * (size_t)(layer ? 65536 : 49152);
        const int NW = layer ? 16 : 12;
        for (int i = 0; i < NW; ++i) {
            const int ix = i * 512 + tid;
            ((bf16x8*)lds)[ix] = *(const bf16x8*)(wsrc + (size_t)ix * 8);
        }
    }
    __syncthreads();
    const bf16* wlo_blk = (layer ? a.W1lof : a.W0lof)
                          + (size_t)ng * (size_t)(layer ? 65536 : 49152);

    // pointwise ownership: (m, jp..jp+1), 512 threads cover 64 x 8 pairs
    const int m  = (tid >> 3) & 63;
    const int jp = (tid & 7) * 2;
    const int j  = j0 + jp;
    const float* bs = layer ? a.bsum1 : a.bsum0;
    const float bI0 = bs[j],        bI1 = bs[j + 1];
    const float bF0 = bs[512 + j],  bF1 = bs[512 + j + 1];
    const float bG0 = bs[1024 + j], bG1 = bs[1024 + j + 1];
    const float bO0 = bs[1536 + j], bO1 = bs[1536 + j + 1];
    float c0r = 0.f, c1r = 0.f;
    const size_t hix = (size_t)(bm0 + m) * H + j;   // 4B-aligned (j even)

    unsigned int* bar = a.bar + mg * 64;
    constexpr unsigned HB = (unsigned)(B * H * 2);   // state buffer bytes

    if (layer == 0) {
        // full W-lo column for wc: 24 frags = 96 VGPR, loaded once
        bf16x8 wlo_own[24];
#pragma unroll
        for (int S = 0; S < 24; ++S)
            wlo_own[S] = *(const bf16x8*)(wlo_blk + (size_t)((S * 4 + wc) * 64 + lane) * 8);

        for (int t = 0; t <= L; ++t) {
            const int p0 = t & 1;
            if (t < L) {
                const bf16* a0h = a.ehi + (size_t)t * B * P;
                const bf16* a0l = a.elo + (size_t)t * B * P;
                const i32x4 r1h = make_rsrc(a.h0hi[1 - p0], HB);
                const i32x4 r1l = make_rsrc(a.h0lo[1 - p0], HB);
                tick_body<12, 0>(tid, lane, wr2, wc, grow, kin, slot,
                                 a0h, a0l, r1h, r1l, lds, wlo_own,
                                 bI0, bI1, bF0, bF1, bG0, bG1, bO0, bO1,
                                 c0r, c1r,
                                 (unsigned int*)(a.h0hi[p0] + hix),
                                 (unsigned int*)(a.h0lo[p0] + hix), m, jp);
            }
            group_bar(bar, t);
        }
    } else {
        // full W-lo column for wc: 32 frags = 128 VGPR, loaded once
        bf16x8 wlo_own[32];
#pragma unroll
        for (int S = 0; S < 32; ++S)
            wlo_own[S] = *(const bf16x8*)(wlo_blk + (size_t)((S * 4 + wc) * 64 + lane) * 8);

        for (int t = 0; t <= L; ++t) {
            const int p0 = t & 1;
            if (t >= 1) {
                // cross-XCD: h0[t-1] (written on XCD mg) via sc1 cload
                const bf16* a0h = a.h0hi[1 - p0];
                const bf16* a0l = a.h0lo[1 - p0];
                // co-XCD: h1[t-2] via sc0
                const i32x4 r1h = make_rsrc(a.h1hi[p0], HB);
                const i32x4 r1l = make_rsrc(a.h1lo[p0], HB);
                tick_body<16, 1>(tid, lane, wr2, wc, grow, kin, slot,
                                 a0h, a0l, r1h, r1l, lds, wlo_own,
                                 bI0, bI1, bF0, bF1, bG0, bG1, bO0, bO1,
                                 c0r, c1r,
                                 (unsigned int*)(a.h1hi[1 - p0] + hix),
                                 (unsigned int*)(a.h1lo[1 - p0] + hix), m, jp);
            }
            group_bar(bar, t);
        }
    }
}

// ---------------------------------------------------------------------------
// head: per batch row b, j = joint_index[b]
// ---------------------------------------------------------------------------
__global__ __launch_bounds__(256) void head_kernel(
    const bf16* __restrict__ h_hi, const bf16* __restrict__ h_lo,
    const int* __restrict__ joint_index,
    const float* __restrict__ Wh1, const float* __restrict__ bh1,
    const float* __restrict__ Wh2, const float* __restrict__ bh2,
    float* __restrict__ out)
{
    const int b = blockIdx.x;
    const int t = threadIdx.x;
    const int j = joint_index[b];
    __shared__ float hs[H];
    __shared__ float zs[M];

    hs[t]       = (float)h_hi[(size_t)b * H + t]       + (float)h_lo[(size_t)b * H + t];
    hs[t + 256] = (float)h_hi[(size_t)b * H + 256 + t] + (float)h_lo[(size_t)b * H + 256 + t];
    __syncthreads();

    float acc = bh1[j * M + t];
    const float* w = Wh1 + (size_t)j * H * M + t;
#pragma unroll 8
    for (int k = 0; k < H; ++k) acc = fmaf(hs[k], w[(size_t)k * M], acc);

    zs[t] = gelu_exact(acc);
    __syncthreads();

    if (t < HOR) {
        float a = bh2[j * HOR + t];
        const float* w2 = Wh2 + (size_t)j * M * HOR + t;
        for (int mm = 0; mm < M; ++mm) a = fmaf(zs[mm], w2[(size_t)mm * HOR], a);
        out[(size_t)b * HOR + t] = a;
    }
}

// ---------------------------------------------------------------------------
extern "C" void kernel_launch(void* const* d_in, const int* in_sizes, int n_in,
                              void* d_out, int out_size, void* d_ws, size_t ws_size,
                              hipStream_t stream)
{
    const float* x     = (const float*)d_in[0];
    const int*   joint = (const int*)  d_in[1];
    const float* Wp    = (const float*)d_in[2];
    const float* bp    = (const float*)d_in[3];
    const float* gamma = (const float*)d_in[4];
    const float* beta  = (const float*)d_in[5];
    const float* Wih0  = (const float*)d_in[6];
    const float* Whh0  = (const float*)d_in[7];
    const float* bih0  = (const float*)d_in[8];
    const float* bhh0  = (const float*)d_in[9];
    const float* Wih1  = (const float*)d_in[10];
    const float* Whh1  = (const float*)d_in[11];
    const float* bih1  = (const float*)d_in[12];
    const float* bhh1  = (const float*)d_in[13];
    const float* Wh1   = (const float*)d_in[14];
    const float* bh1   = (const float*)d_in[15];
    const float* Wh2   = (const float*)d_in[16];
    const float* bh2   = (const float*)d_in[17];
    float* out = (float*)d_out;

    char* base = (char*)d_ws;
    size_t off = 0;
    auto take = [&](size_t nbytes) -> void* {
        void* p = base + off;
        off = (off + nbytes + 255) & ~(size_t)255;
        return p;
    };

    RArgs a;
    a.W0hif = (bf16*)take((size_t)G * K0 * 2);
    a.W0lof = (bf16*)take((size_t)G * K0 * 2);
    a.W1hif = (bf16*)take((size_t)G * K1 * 2);
    a.W1lof = (bf16*)take((size_t)G * K1 * 2);
    a.bsum0 = (float*)take(G * 4);
    a.bsum1 = (float*)take(G * 4);

    const size_t states_off = off;
    for (int i = 0; i < 2; ++i) a.h0hi[i] = (bf16*)take((size_t)B * H * 2);
    for (int i = 0; i < 2; ++i) a.h0lo[i] = (bf16*)take((size_t)B * H * 2);
    for (int i = 0; i < 2; ++i) a.h1hi[i] = (bf16*)take((size_t)B * H * 2);
    for (int i = 0; i < 2; ++i) a.h1lo[i] = (bf16*)take((size_t)B * H * 2);
    a.bar = (unsigned int*)take(4 * 256);
    const size_t states_bytes = off - states_off;   // h bufs + bar -> zeroed

    bf16* ehi = (bf16*)take((size_t)L * B * P * 2);
    bf16* elo = (bf16*)take((size_t)L * B * P * 2);
    a.use_elo = (off <= ws_size) ? 1 : 0;
    if (!a.use_elo) elo = ehi;
    a.ehi = ehi; a.elo = elo;

    prep_w_frag<<<dim3(32, K0 / 32, 4), 64, 0, stream>>>(Wih0, Whh0, P,
                                                         (bf16*)a.W0hif, (bf16*)a.W0lof);
    prep_w_frag<<<dim3(32, K1 / 32, 4), 64, 0, stream>>>(Wih1, Whh1, H,
                                                         (bf16*)a.W1hif, (bf16*)a.W1lof);
    prep_bias<<<8, 256, 0, stream>>>(bih0, bhh0, bih1, bhh1,
                                     (float*)a.bsum0, (float*)a.bsum1);
    hipMemsetAsync(base + states_off, 0, states_bytes, stream);
    emb_kernel<<<B * L, 256, 0, stream>>>(x, Wp, bp, gamma, beta, ehi, elo, a.use_elo);

    hipFuncSetAttribute((const void*)recurrence_kernel,
                        hipFuncAttributeMaxDynamicSharedMemorySize, LDS_BYTES);
    void* params[] = { &a };
    hipLaunchCooperativeKernel((void*)recurrence_kernel, dim3(256), dim3(512),
                               params, LDS_BYTES, stream);

    // final h1 (step 511) written at tick t=512 into buf[1-(512&1)] = buf 1
    head_kernel<<<B, 256, 0, stream>>>(a.h1hi[1], a.h1lo[1], joint, Wh1, bh1, Wh2, bh2, out);
}